// Round 1
// 340.454 us; speedup vs baseline: 1.1378x; 1.1378x over previous
//
#include <hip/hip_runtime.h>
#include <math.h>

#define B_ 4
#define P_ 64
#define D_ 768
#define N_ 2048
#define R_ 12
#define K_ 16
#define Q_ 256  // B_*P_
#define SSPLIT_ 4    // split-K planes for scores
#define SPLITS_ 16   // split-K planes for out
#define BK_ 32
#define NEG_INF_ -3.0e38f

// ---------------- K1: fused front end ---------------------------------
// blocks [0,512):    scores = pos(256xD) @ kp^T, RAW kp (invnorm applied in
//                    top-k: pos.(kp*inv) == (pos.kp)*inv), split-K=4 over D.
//                    512 blocks = 2 blocks/CU (was 1 -> no latency hiding).
// blocks [512,1024): key normalization, 1 row per wave, + invnorm table.
// blocks [1024,5120): A_sum[n,m] = sum_r adj[r,n,m]  (201 MB HBM stream).
// All three are mutually independent -> asum's HBM leg (was a serial ~33us)
// now runs underneath the scores GEMM.
__global__ __launch_bounds__(256) void k_front(const float* __restrict__ pos,
                                               const float* __restrict__ kp,
                                               const float* __restrict__ adj,
                                               float* __restrict__ spart,
                                               float* __restrict__ keys,
                                               float* __restrict__ invn,
                                               float* __restrict__ asum) {
    __shared__ float Ast[BK_][68];
    __shared__ float Bst[BK_][68];
    int bid = blockIdx.x;
    int tid = threadIdx.x;
    if (bid < 512) {
        // ---- scores tile (64x64, BK=32, 4x4/thread), raw kp ----
        int z = bid >> 7;          // 0..3 -> D quarters
        int t = bid & 127;         // 32 n-tiles x 4 q-tiles
        int n0 = (t & 31) * 64, q0 = (t >> 5) * 64;
        int tx = tid & 15, ty = tid >> 4;
        float acc[4][4] = {};
        for (int kb = z * (D_ / SSPLIT_); kb < (z + 1) * (D_ / SSPLIT_); kb += BK_) {
            #pragma unroll
            for (int e = 0; e < 2; e++) {
                int elem = tid + e * 256;
                int row = elem >> 3, c4 = elem & 7;
                float4 v = *(const float4*)(pos + (size_t)(q0 + row) * D_ + kb + c4 * 4);
                Ast[c4 * 4 + 0][row] = v.x; Ast[c4 * 4 + 1][row] = v.y;
                Ast[c4 * 4 + 2][row] = v.z; Ast[c4 * 4 + 3][row] = v.w;
            }
            #pragma unroll
            for (int e = 0; e < 2; e++) {
                int elem = tid + e * 256;
                int row = elem >> 3, c4 = elem & 7;
                float4 v = *(const float4*)(kp + (size_t)(n0 + row) * D_ + kb + c4 * 4);
                Bst[c4 * 4 + 0][row] = v.x; Bst[c4 * 4 + 1][row] = v.y;
                Bst[c4 * 4 + 2][row] = v.z; Bst[c4 * 4 + 3][row] = v.w;
            }
            __syncthreads();
            #pragma unroll 4
            for (int kk = 0; kk < BK_; kk++) {
                float4 a = *(const float4*)&Ast[kk][ty * 4];
                float4 b = *(const float4*)&Bst[kk][tx * 4];
                float av[4] = {a.x, a.y, a.z, a.w};
                float bv[4] = {b.x, b.y, b.z, b.w};
                #pragma unroll
                for (int i = 0; i < 4; i++)
                    #pragma unroll
                    for (int j = 0; j < 4; j++)
                        acc[i][j] += av[i] * bv[j];
            }
            __syncthreads();
        }
        float* base = spart + (size_t)z * Q_ * N_;
        #pragma unroll
        for (int i = 0; i < 4; i++) {
            float4 v = {acc[i][0], acc[i][1], acc[i][2], acc[i][3]};
            *(float4*)(base + (size_t)(q0 + ty * 4 + i) * N_ + n0 + tx * 4) = v;
        }
    } else if (bid < 1024) {
        // ---- key norm: one row per wave (12 floats/lane) ----
        int row = (bid - 512) * 4 + (tid >> 6);
        int lane = tid & 63;
        const float4* src = (const float4*)(kp + (size_t)row * D_);
        float4 a = src[lane], b = src[lane + 64], c = src[lane + 128];
        float ss = a.x * a.x + a.y * a.y + a.z * a.z + a.w * a.w
                 + b.x * b.x + b.y * b.y + b.z * b.z + b.w * b.w
                 + c.x * c.x + c.y * c.y + c.z * c.z + c.w * c.w;
        #pragma unroll
        for (int off = 32; off > 0; off >>= 1) ss += __shfl_down(ss, off, 64);
        ss = __shfl(ss, 0, 64);
        float inv = 1.0f / sqrtf(ss + 1e-12f);
        float4* dst = (float4*)(keys + (size_t)row * D_);
        float4 oa = {a.x * inv, a.y * inv, a.z * inv, a.w * inv};
        float4 ob = {b.x * inv, b.y * inv, b.z * inv, b.w * inv};
        float4 oc = {c.x * inv, c.y * inv, c.z * inv, c.w * inv};
        dst[lane] = oa; dst[lane + 64] = ob; dst[lane + 128] = oc;
        if (lane == 0) invn[row] = inv;
    } else {
        // ---- A_sum: 201 MB mandatory HBM read ----
        size_t i = (size_t)(bid - 1024) * 256 + tid;
        const float4* a4 = (const float4*)adj;
        const size_t plane = (size_t)N_ * N_ / 4;
        float4 acc = {0.f, 0.f, 0.f, 0.f};
        #pragma unroll
        for (int r = 0; r < R_; r++) {
            float4 v = a4[(size_t)r * plane + i];
            acc.x += v.x; acc.y += v.y; acc.z += v.z; acc.w += v.w;
        }
        ((float4*)asum)[i] = acc;
    }
}

// ---------------- K2: fused top-16 + softmax + neighbor gather ---------
// Phase A: register-resident top-16 (per-wave shuffle butterflies, one
// wave merges 4x16 candidates). Applies invnorm at load. Ties -> smaller
// index (matches lax.top_k). Results stay in LDS (no global round-trip).
// Phase B: nei[q,:] = sum_k w_k * A_sum[idx_k,:] (L3-resident gather).
__global__ __launch_bounds__(256) void k_topk_nei(const float* __restrict__ spart,
                                                  const float* __restrict__ invn,
                                                  const float* __restrict__ asum,
                                                  float* __restrict__ nei) {
    int q = blockIdx.x, tid = threadIdx.x;
    int w = tid >> 6, lane = tid & 63;
    int base = w * 512 + lane;
    const float* r0 = spart + (size_t)q * N_;
    const size_t pl = (size_t)Q_ * N_;
    float v[8];
    #pragma unroll
    for (int j = 0; j < 8; j++) {
        int n = base + j * 64;
        v[j] = (r0[n] + r0[pl + n] + r0[2 * pl + n] + r0[3 * pl + n]) * invn[n];
    }
    __shared__ float cv[64];
    __shared__ int ci[64];
    __shared__ float sw[K_];
    __shared__ int si[K_];
    for (int r = 0; r < K_; r++) {
        float bv = NEG_INF_;
        int bi = 0;
        #pragma unroll
        for (int j = 0; j < 8; j++) {
            int n = base + j * 64;
            if (v[j] > bv) { bv = v[j]; bi = n; }  // ascending n: first max kept
        }
        #pragma unroll
        for (int off = 1; off < 64; off <<= 1) {
            float ov = __shfl_xor(bv, off, 64);
            int oi = __shfl_xor(bi, off, 64);
            if (ov > bv || (ov == bv && oi < bi)) { bv = ov; bi = oi; }
        }
        if (lane == 0) { cv[w * K_ + r] = bv; ci[w * K_ + r] = bi; }
        #pragma unroll
        for (int j = 0; j < 8; j++)
            if (base + j * 64 == bi) v[j] = NEG_INF_;
    }
    __syncthreads();
    if (w == 0) {
        float mv = cv[lane];
        int mi = ci[lane];  // 64 candidates, all n distinct
        float sel_v = NEG_INF_;
        int sel_i = 0;
        for (int r = 0; r < K_; r++) {
            float bv = mv;
            int bi = mi;
            #pragma unroll
            for (int off = 1; off < 64; off <<= 1) {
                float ov = __shfl_xor(bv, off, 64);
                int oi = __shfl_xor(bi, off, 64);
                if (ov > bv || (ov == bv && oi < bi)) { bv = ov; bi = oi; }
            }
            if (lane == r) { sel_v = bv; sel_i = bi; }
            if (mi == bi) mv = NEG_INF_;
        }
        // softmax over lanes 0..15 (lane 0 holds the max: rounds descend)
        float m = __shfl(sel_v, 0, 64);
        float e = (lane < K_) ? expf(sel_v - m) : 0.0f;
        float sum = e;
        #pragma unroll
        for (int off = 1; off < 64; off <<= 1) sum += __shfl_xor(sum, off, 64);
        if (lane < K_) { sw[lane] = e / sum; si[lane] = sel_i; }
    }
    __syncthreads();
    float4 acc0 = {0.f, 0.f, 0.f, 0.f};
    float4 acc1 = {0.f, 0.f, 0.f, 0.f};
    #pragma unroll
    for (int k = 0; k < K_; k++) {
        const float4* row = (const float4*)(asum + (size_t)si[k] * N_);
        float wk = sw[k];
        float4 v0 = row[tid], v1 = row[tid + 256];
        acc0.x += wk * v0.x; acc0.y += wk * v0.y; acc0.z += wk * v0.z; acc0.w += wk * v0.w;
        acc1.x += wk * v1.x; acc1.y += wk * v1.y; acc1.z += wk * v1.z; acc1.w += wk * v1.w;
    }
    float4* dst = (float4*)(nei + (size_t)q * N_);
    dst[tid] = acc0;
    dst[tid + 256] = acc1;
}

// ---------------- K3: out_part[z] = nei (256 x 128-slice) @ keys -------
// Split-K=16 over N: 768 blocks = 3 blocks/CU (was 1.5). Private partials
// (plain stores; atomics ping-pong across non-coherent XCD L2s).
__global__ __launch_bounds__(256) void k_out_part(const float* __restrict__ nei,
                                                  const float* __restrict__ keys,
                                                  float* __restrict__ part) {
    __shared__ float Ast[BK_][68];
    __shared__ float Bst[BK_][68];
    int tid = threadIdx.x;
    int tx = tid & 15, ty = tid >> 4;
    int d0 = blockIdx.x * 64;
    int q0 = blockIdx.y * 64;
    int z = blockIdx.z;
    float acc[4][4] = {};
    for (int kb = z * (N_ / SPLITS_); kb < (z + 1) * (N_ / SPLITS_); kb += BK_) {
        #pragma unroll
        for (int e = 0; e < 2; e++) {
            int elem = tid + e * 256;
            int row = elem >> 3, c4 = elem & 7;
            float4 v = *(const float4*)(nei + (size_t)(q0 + row) * N_ + kb + c4 * 4);
            Ast[c4 * 4 + 0][row] = v.x; Ast[c4 * 4 + 1][row] = v.y;
            Ast[c4 * 4 + 2][row] = v.z; Ast[c4 * 4 + 3][row] = v.w;
        }
        #pragma unroll
        for (int e = 0; e < 2; e++) {
            int elem = tid + e * 256;
            int kr = elem >> 4, c4 = elem & 15;
            float4 v = *(const float4*)(keys + (size_t)(kb + kr) * D_ + d0 + c4 * 4);
            *(float4*)&Bst[kr][c4 * 4] = v;
        }
        __syncthreads();
        #pragma unroll 4
        for (int kk = 0; kk < BK_; kk++) {
            float4 a = *(const float4*)&Ast[kk][ty * 4];
            float4 b = *(const float4*)&Bst[kk][tx * 4];
            float av[4] = {a.x, a.y, a.z, a.w};
            float bv[4] = {b.x, b.y, b.z, b.w};
            #pragma unroll
            for (int i = 0; i < 4; i++)
                #pragma unroll
                for (int j = 0; j < 4; j++)
                    acc[i][j] += av[i] * bv[j];
        }
        __syncthreads();
    }
    float* base = part + (size_t)z * Q_ * D_;
    #pragma unroll
    for (int i = 0; i < 4; i++) {
        float4 v = {acc[i][0], acc[i][1], acc[i][2], acc[i][3]};
        *(float4*)(base + (size_t)(q0 + ty * 4 + i) * D_ + d0 + tx * 4) = v;
    }
}

// ---------------- K4: out = sum_z part[z] ------------------------------
__global__ __launch_bounds__(256) void k_reduce(const float* __restrict__ part,
                                                float* __restrict__ out) {
    int i = blockIdx.x * 256 + threadIdx.x;
    const float4* p4 = (const float4*)part;
    const int plane = Q_ * D_ / 4;
    float4 acc = {0.f, 0.f, 0.f, 0.f};
    #pragma unroll
    for (int z = 0; z < SPLITS_; z++) {
        float4 v = p4[(size_t)z * plane + i];
        acc.x += v.x; acc.y += v.y; acc.z += v.z; acc.w += v.w;
    }
    ((float4*)out)[i] = acc;
}

extern "C" void kernel_launch(void* const* d_in, const int* in_sizes, int n_in,
                              void* d_out, int out_size, void* d_ws, size_t ws_size,
                              hipStream_t stream) {
    const float* pos = (const float*)d_in[0];   // (4,64,768)
    const float* kp  = (const float*)d_in[1];   // (2048,768)
    const float* adj = (const float*)d_in[2];   // (12,2048,2048)
    // d_in[3] is k==16, hard-coded.
    float* out = (float*)d_out;

    float* ws     = (float*)d_ws;
    float* keys   = ws;                              // 1,572,864 f
    float* invn   = keys + (size_t)N_ * D_;          //     2,048 f
    float* asum   = invn + N_;                       // 4,194,304 f (16 MB)
    float* spart  = asum + (size_t)N_ * N_;          // 4 x 524,288 f (split-K scores)
    float* nei    = spart + (size_t)SSPLIT_ * Q_ * N_; // 524,288 f
    // Split-K output partials (16 * 256*768 f = 12 MB) aliased onto asum
    // (dead after K2's gather; same-stream ordering makes it safe).
    float* part   = asum;

    k_front<<<5120, 256, 0, stream>>>(pos, kp, adj, spart, keys, invn, asum);
    k_topk_nei<<<Q_, 256, 0, stream>>>(spart, invn, asum, nei);
    k_out_part<<<dim3(12, 4, SPLITS_), 256, 0, stream>>>(nei, keys, part);
    k_reduce<<<192, 256, 0, stream>>>(part, out);
}